// Round 7
// baseline (355.681 us; speedup 1.0000x reference)
//
#include <hip/hip_runtime.h>
#include <float.h>

#define NTOK 32768  // 16 * 2048 tokens per modality

typedef __attribute__((ext_vector_type(8))) short bf16x8;
typedef __attribute__((ext_vector_type(4))) float f32x4;

// ---- ws byte layout ----
#define WSB_W2    0          // 1280 floats
#define WSB_X2    8192       // 5*NTOK floats (655360 B)
#define WSB_CNT   663808     // 5 ints
#define WSB_LIST  664064     // 5*NTOK ints (655360 B)
#define WSB_WSP   1572864    // swizzled bf16 hi/lo planes (852 KB)

#define GLOAD16(g, l)                                                        \
  __builtin_amdgcn_global_load_lds(                                          \
      (__attribute__((address_space(1))) const void*)(const void*)(g),       \
      (__attribute__((address_space(3))) void*)(void*)(l), 16, 0, 0)

__device__ __forceinline__ unsigned short f2bf(float f) {
    unsigned u = __float_as_uint(f);
    return (unsigned short)((u + 0x7FFFu + ((u >> 16) & 1u)) >> 16);
}
__device__ __forceinline__ float bf2f(unsigned short h) {
    return __uint_as_float(((unsigned)h) << 16);
}

// ================= numpy pairwise-sum replica (fp32) for ||w||^2 ============
__device__ __forceinline__ float pw_sq_block_g(const float* __restrict__ a, int n) {
    float r[8];
    #pragma unroll
    for (int j = 0; j < 8; ++j) r[j] = __fmul_rn(a[j], a[j]);
    for (int i = 8; i < n; i += 8)
        #pragma unroll
        for (int j = 0; j < 8; ++j)
            r[j] = __fadd_rn(r[j], __fmul_rn(a[i + j], a[i + j]));
    return __fadd_rn(__fadd_rn(__fadd_rn(r[0], r[1]), __fadd_rn(r[2], r[3])),
                     __fadd_rn(__fadd_rn(r[4], r[5]), __fadd_rn(r[6], r[7])));
}

__global__ void w2_kernel(const float* __restrict__ W, float* __restrict__ w2,
                          int K, int D) {
    int k = blockIdx.x * blockDim.x + threadIdx.x;
    if (k >= K) return;
    const float* row = W + (size_t)k * D;
    float s = (D > 128)
        ? __fadd_rn(pw_sq_block_g(row, 128), pw_sq_block_g(row + 128, D - 128))
        : pw_sq_block_g(row, D);
    w2[k] = s;
}

// ---- split W into bf16 hi/lo planes, pre-swizzled per 16-code tile ----
__global__ void wsplit_kernel(const float* __restrict__ W,
                              unsigned char* __restrict__ dst, int K, int D) {
    int i = blockIdx.x * 256 + threadIdx.x;  // element-pair index
    if (i >= K * D / 2) return;
    int k  = i / (D / 2);
    int d2 = i % (D / 2);
    float2 v = *(const float2*)(W + (size_t)k * D + 2 * d2);
    unsigned short h0 = f2bf(v.x), h1 = f2bf(v.y);
    unsigned short l0 = f2bf(__fsub_rn(v.x, bf2f(h0)));
    unsigned short l1 = f2bf(__fsub_rn(v.y, bf2f(h1)));
    int tileb = 16 * D * 2;
    int o  = (k & 15) * (D * 2) + d2 * 4;
    int os = o ^ ((k & 7) << 4);             // XOR swizzle (read side matches)
    size_t tb = (size_t)(k >> 4) * (2 * (size_t)tileb);
    *(unsigned int*)(dst + tb + os)         = (unsigned)h0 | ((unsigned)h1 << 16);
    *(unsigned int*)(dst + tb + tileb + os) = (unsigned)l0 | ((unsigned)l1 << 16);
}

// ---- MFMA bf16-split screen: top-2 argmin + gather + loss ----
template <int D, int K>
__global__ __launch_bounds__(256)
void vq_mfma(const float* __restrict__ X, const float* __restrict__ W,
             const unsigned char* __restrict__ Wsp, const float* __restrict__ w2,
             float* __restrict__ q_out, float* __restrict__ idx_out,
             float* __restrict__ loss_out, float* __restrict__ x2_save,
             int* __restrict__ amb_cnt, int* __restrict__ amb_list,
             float inv_nd)
{
    constexpr int DS    = D / 32;       // MFMA K-steps
    constexpr int NT    = K / 16;       // code tiles
    constexpr int TILEB = 16 * D * 2;   // bytes per plane-tile
    constexpr int STG   = (2 * TILEB) / 4096;  // gload16 iters (256 thr)

    __shared__ __align__(16) unsigned char lds[2 * 2 * TILEB];  // [buf][plane]
    __shared__ int   idx_s[64];
    __shared__ float lred[4];

    const int tid  = threadIdx.x;
    const int lane = tid & 63;
    const int wv   = tid >> 6;
    const int t0   = blockIdx.x * 64;
    const int tw   = t0 + wv * 16 + (lane & 15);   // this lane's token

    // ---- phase 0: numpy-pairwise ||x||^2 (exact replica, lane-split tree) ----
    float x2v;
    {
        const float* xr = X + (size_t)tw * D;
        const int jg = lane >> 4;                  // j-pair group 0..3
        constexpr int B1M = (D > 128) ? 16 : (D / 8);
        float2 v = *(const float2*)(xr + 2 * jg);
        float r0 = __fmul_rn(v.x, v.x), r1 = __fmul_rn(v.y, v.y);
        #pragma unroll
        for (int m = 1; m < B1M; ++m) {
            float2 u = *(const float2*)(xr + 8 * m + 2 * jg);
            r0 = __fadd_rn(r0, __fmul_rn(u.x, u.x));
            r1 = __fadd_rn(r1, __fmul_rn(u.y, u.y));
        }
        float p = __fadd_rn(r0, r1);               // r[2jg]+r[2jg+1]
        p = __fadd_rn(p, __shfl_xor(p, 16, 64));   // (r0+r1)+(r2+r3) | (r4..r7)
        p = __fadd_rn(p, __shfl_xor(p, 32, 64));   // full np combine tree
        x2v = p;
        if (D > 128) {                             // second 128-block (D=256)
            float2 w0 = *(const float2*)(xr + 128 + 2 * jg);
            float s0 = __fmul_rn(w0.x, w0.x), s1 = __fmul_rn(w0.y, w0.y);
            #pragma unroll
            for (int m = 1; m < 16; ++m) {
                float2 u = *(const float2*)(xr + 128 + 8 * m + 2 * jg);
                s0 = __fadd_rn(s0, __fmul_rn(u.x, u.x));
                s1 = __fadd_rn(s1, __fmul_rn(u.y, u.y));
            }
            float q2 = __fadd_rn(s0, s1);
            q2 = __fadd_rn(q2, __shfl_xor(q2, 16, 64));
            q2 = __fadd_rn(q2, __shfl_xor(q2, 32, 64));
            x2v = __fadd_rn(p, q2);
        }
        if ((lane >> 4) == 0) x2_save[tw] = x2v;
    }

    // ---- phase 1: X B-fragments (bf16 hi/lo) into registers ----
    bf16x8 bhi[DS], blo[DS];
    {
        const float* xr = X + (size_t)tw * D + (lane >> 4) * 8;
        #pragma unroll
        for (int ds = 0; ds < DS; ++ds) {
            float4 a = *(const float4*)(xr + ds * 32);
            float4 b = *(const float4*)(xr + ds * 32 + 4);
            float f[8] = {a.x, a.y, a.z, a.w, b.x, b.y, b.z, b.w};
            bf16x8 h, l;
            #pragma unroll
            for (int j = 0; j < 8; ++j) {
                unsigned short hh = f2bf(f[j]);
                h[j] = (short)hh;
                l[j] = (short)f2bf(__fsub_rn(f[j], bf2f(hh)));
            }
            bhi[ds] = h; blo[ds] = l;
        }
    }

    // ---- phase 2: k-loop, double-buffered W tiles, 3-way split MFMA ----
    float b1v = FLT_MAX, b2v = FLT_MAX;
    int   b1i = 0;
    {
        const int row   = lane & 15;               // code within tile
        const int g     = lane >> 4;
        const int abase = row * (D * 2);
        const int sw    = (row & 7) << 4;
        #pragma unroll
        for (int s = 0; s < STG; ++s)
            GLOAD16(Wsp + tid * 16 + s * 4096, lds + tid * 16 + s * 4096);
        __syncthreads();

        for (int kt = 0; kt < NT; ++kt) {
            const int cur = kt & 1;
            if (kt + 1 < NT) {                     // prefetch next tile
                const unsigned char* src = Wsp + (size_t)(kt + 1) * (2 * TILEB);
                unsigned char* dl = lds + (cur ^ 1) * (2 * TILEB);
                #pragma unroll
                for (int s = 0; s < STG; ++s)
                    GLOAD16(src + tid * 16 + s * 4096, dl + tid * 16 + s * 4096);
            }
            const unsigned char* base = lds + cur * (2 * TILEB);
            f32x4 acc0 = {0.f, 0.f, 0.f, 0.f}, acc1 = {0.f, 0.f, 0.f, 0.f};
            #pragma unroll
            for (int ds = 0; ds < DS; ++ds) {
                const int off = (abase + ds * 64 + g * 16) ^ sw;
                bf16x8 ahi = *(const bf16x8*)(base + off);
                bf16x8 alo = *(const bf16x8*)(base + TILEB + off);
                if (ds & 1) {                      // two independent acc chains
                    acc1 = __builtin_amdgcn_mfma_f32_16x16x32_bf16(ahi, bhi[ds], acc1, 0, 0, 0);
                    acc1 = __builtin_amdgcn_mfma_f32_16x16x32_bf16(ahi, blo[ds], acc1, 0, 0, 0);
                    acc1 = __builtin_amdgcn_mfma_f32_16x16x32_bf16(alo, bhi[ds], acc1, 0, 0, 0);
                } else {
                    acc0 = __builtin_amdgcn_mfma_f32_16x16x32_bf16(ahi, bhi[ds], acc0, 0, 0, 0);
                    acc0 = __builtin_amdgcn_mfma_f32_16x16x32_bf16(ahi, blo[ds], acc0, 0, 0, 0);
                    acc0 = __builtin_amdgcn_mfma_f32_16x16x32_bf16(alo, bhi[ds], acc0, 0, 0, 0);
                }
            }
            const int kb = kt * 16 + g * 4;        // codes this lane scored
            #pragma unroll
            for (int r = 0; r < 4; ++r) {          // k-ascending, strict <
                float s = fmaf(-2.f, __fadd_rn(acc0[r], acc1[r]), w2[kb + r]);
                if (s < b1v)      { b2v = b1v; b1v = s; b1i = kb + r; }
                else if (s < b2v) { b2v = s; }
            }
            __syncthreads();
        }
    }

    // ---- phase 3: merge top-2 across the 4 code-groups (tie-break by index) --
    {
        float v1 = b1v, v2 = b2v; int i1 = b1i;
        #pragma unroll
        for (int m = 16; m < 64; m <<= 1) {
            float o1 = __shfl_xor(v1, m, 64);
            float o2 = __shfl_xor(v2, m, 64);
            int   oi = __shfl_xor(i1, m, 64);
            bool better = (o1 < v1) || (o1 == v1 && oi < i1);
            float nb2 = better ? fminf(v1, o2) : fminf(o1, v2);
            if (better) { v1 = o1; i1 = oi; }
            v2 = nb2;
        }
        if ((lane >> 4) == 0) {
            idx_s[tw - t0] = i1;
            idx_out[tw] = (float)i1;
            // per-token margin: np contaminates comparisons by <= 4u*(x2+w2)
            // (u=2^-24); 2.6e-7 = 4u*1.09 headroom; +4e-6 covers screen error
            float margin = fmaf(x2v, 2.6e-7f, 4e-6f);
            if (v2 - v1 <= margin) {               // near-tie: exact rescore
                int p = atomicAdd(amb_cnt, 1);
                amb_list[p] = tw;
            }
        }
    }
    __syncthreads();

    // ---- phase 4: gather q = W[idx] + commitment-loss partial ----
    float lp = 0.f;
    for (int i = tid; i < 64 * (D / 4); i += 256) {
        int d4 = i % (D / 4);
        int t  = i / (D / 4);
        int k  = idx_s[t];
        const float4 w = *(const float4*)(W + (size_t)k * D + d4 * 4);
        const float4 x = *(const float4*)(X + (size_t)(t0 + t) * D + d4 * 4);
        *(float4*)(q_out + (size_t)(t0 + t) * D + d4 * 4) = w;
        float dx;
        dx = w.x - x.x; lp = fmaf(dx, dx, lp);
        dx = w.y - x.y; lp = fmaf(dx, dx, lp);
        dx = w.z - x.z; lp = fmaf(dx, dx, lp);
        dx = w.w - x.w; lp = fmaf(dx, dx, lp);
    }
    #pragma unroll
    for (int off = 32; off > 0; off >>= 1) lp += __shfl_down(lp, off, 64);
    if ((tid & 63) == 0) lred[tid >> 6] = lp;
    __syncthreads();
    if (tid == 0) {
        float tot = (lred[0] + lred[1]) + (lred[2] + lred[3]);
        atomicAdd(loss_out, tot * inv_nd);
    }
}

// ---- exact rescore of ambiguous tokens; one token/block, wave-coop dots ----
template <int D, int K>
__global__ __launch_bounds__(256)
void cleanup_kernel(const float* __restrict__ X, const float* __restrict__ W,
                    const float* __restrict__ w2, const float* __restrict__ x2,
                    float* __restrict__ q_out, float* __restrict__ idx_out,
                    float* __restrict__ loss_out,
                    const int* __restrict__ cnt, const int* __restrict__ list,
                    float inv_nd)
{
    constexpr int EPL = D / 64;       // depth elems per lane
    constexpr int CPW = K / 4;        // codes per wave
    const int n    = *cnt;
    const int tid  = threadIdx.x;
    const int lane = tid & 63;
    const int wv   = tid >> 6;

    __shared__ float rv[4];
    __shared__ int   ri[4];
    __shared__ int   s_new, s_old;

    for (int e = blockIdx.x; e < n; e += gridDim.x) {
        __syncthreads();              // protect rv/ri/s_* reuse across tokens
        const int t = list[e];
        // lane's X depth-fragment in f64 registers (coalesced, loaded once)
        double xd[EPL];
        {
            const float* xp = X + (size_t)t * D + lane * EPL;
            if constexpr (EPL == 4) {
                float4 v = *(const float4*)xp;
                xd[0] = v.x; xd[1] = v.y; xd[2] = v.z; xd[3] = v.w;
            } else if constexpr (EPL == 2) {
                float2 v = *(const float2*)xp;
                xd[0] = v.x; xd[1] = v.y;
            } else {
                xd[0] = xp[0];
            }
        }
        const float x2t = x2[t];
        float bv = FLT_MAX; int bk = 0;
        for (int c = 0; c < CPW; ++c) {           // codes independent -> pipelines
            const int k = wv * CPW + c;
            const float* wp = W + (size_t)k * D + lane * EPL;
            double a = 0.0;
            if constexpr (EPL == 4) {
                float4 v = *(const float4*)wp;    // coalesced 1KB/wave
                a = fma((double)v.x, xd[0], a);
                a = fma((double)v.y, xd[1], a);
                a = fma((double)v.z, xd[2], a);
                a = fma((double)v.w, xd[3], a);
            } else if constexpr (EPL == 2) {
                float2 v = *(const float2*)wp;
                a = fma((double)v.x, xd[0], a);
                a = fma((double)v.y, xd[1], a);
            } else {
                a = (double)wp[0] * xd[0];
            }
            #pragma unroll
            for (int off = 32; off; off >>= 1) a += __shfl_down(a, off, 64);
            if (lane == 0) {                      // c ascending -> first occurrence
                float m = (float)a;               // fl32(f64 dot)
                float s = __fsub_rn(__fadd_rn(x2t, w2[k]), __fmul_rn(2.0f, m));
                if (s < bv) { bv = s; bk = k; }
            }
        }
        if (lane == 0) { rv[wv] = bv; ri[wv] = bk; }
        __syncthreads();
        if (tid == 0) {
            float B = rv[0]; int BI = ri[0];
            #pragma unroll
            for (int r = 1; r < 4; ++r)
                if (rv[r] < B || (rv[r] == B && ri[r] < BI)) { B = rv[r]; BI = ri[r]; }
            int oldk = (int)idx_out[t];
            s_old = oldk; s_new = BI;
            if (BI != oldk) idx_out[t] = (float)BI;
        }
        __syncthreads();
        const int nk = s_new, ok = s_old;
        if (nk != ok) {                           // rare: patch q row + loss
            const float* xr = X + (size_t)t * D;
            const float* wn = W + (size_t)nk * D;
            const float* wo = W + (size_t)ok * D;
            float dl = 0.f;
            for (int d = tid; d < D; d += 256) {
                float xv = xr[d], a = wn[d], b = wo[d];
                q_out[(size_t)t * D + d] = a;
                float da = a - xv, db = b - xv;
                dl += da * da - db * db;
            }
            #pragma unroll
            for (int off = 32; off; off >>= 1) dl += __shfl_down(dl, off, 64);
            if (lane == 0 && dl != 0.f) atomicAdd(loss_out, dl * inv_nd);
        }
    }
}

extern "C" void kernel_launch(void* const* d_in, const int* in_sizes, int n_in,
                              void* d_out, int out_size, void* d_ws, size_t ws_size,
                              hipStream_t stream)
{
    const float* x_hand = (const float*)d_in[0];
    const float* W_hand = (const float*)d_in[1];
    const float* x_loc  = (const float*)d_in[2];
    const float* W_loc  = (const float*)d_in[3];
    const float* x_ori  = (const float*)d_in[4];
    const float* W_ori  = (const float*)d_in[5];
    const float* x_mov  = (const float*)d_in[6];
    const float* W_mov  = (const float*)d_in[7];
    const float* x_nmf  = (const float*)d_in[8];
    const float* W_nmf  = (const float*)d_in[9];

    float* out = (float*)d_out;
    float* q_hand = out;
    float* q_loc  = out + 8388608;
    float* q_ori  = out + 12582912;
    float* q_mov  = out + 14680064;
    float* q_nmf  = out + 18874368;
    float* i_hand = out + 20971520;
    float* i_loc  = out + 21004288;
    float* i_ori  = out + 21037056;
    float* i_mov  = out + 21069824;
    float* i_nmf  = out + 21102592;
    float* loss   = out + 21135360;

    unsigned char* wsb = (unsigned char*)d_ws;
    float* w2b = (float*)(wsb + WSB_W2);
    float* w2_hand = w2b, *w2_loc = w2b + 512, *w2_ori = w2b + 768,
         * w2_mov = w2b + 896, *w2_nmf = w2b + 1152;
    float* x2b = (float*)(wsb + WSB_X2);
    int*   cnt = (int*)(wsb + WSB_CNT);
    int*   lst = (int*)(wsb + WSB_LIST);
    unsigned char* wsp_hand = wsb + WSB_WSP;            // 512*256*2*2 = 524288
    unsigned char* wsp_loc  = wsp_hand + 524288;        // 131072
    unsigned char* wsp_ori  = wsp_loc + 131072;         // 32768
    unsigned char* wsp_mov  = wsp_ori + 32768;          // 131072
    unsigned char* wsp_nmf  = wsp_mov + 131072;         // 32768

    hipMemsetAsync(loss, 0, sizeof(float), stream);
    hipMemsetAsync(cnt, 0, 5 * sizeof(int), stream);

    w2_kernel<<<2, 256, 0, stream>>>(W_hand, w2_hand, 512, 256);
    w2_kernel<<<1, 256, 0, stream>>>(W_loc,  w2_loc,  256, 128);
    w2_kernel<<<1, 256, 0, stream>>>(W_ori,  w2_ori,  128, 64);
    w2_kernel<<<1, 256, 0, stream>>>(W_mov,  w2_mov,  256, 128);
    w2_kernel<<<1, 256, 0, stream>>>(W_nmf,  w2_nmf,  128, 64);

    wsplit_kernel<<<256, 256, 0, stream>>>(W_hand, wsp_hand, 512, 256);
    wsplit_kernel<<<64,  256, 0, stream>>>(W_loc,  wsp_loc,  256, 128);
    wsplit_kernel<<<16,  256, 0, stream>>>(W_ori,  wsp_ori,  128, 64);
    wsplit_kernel<<<64,  256, 0, stream>>>(W_mov,  wsp_mov,  256, 128);
    wsplit_kernel<<<16,  256, 0, stream>>>(W_nmf,  wsp_nmf,  128, 64);

    vq_mfma<256, 512><<<NTOK / 64, 256, 0, stream>>>(
        x_hand, W_hand, wsp_hand, w2_hand, q_hand, i_hand, loss,
        x2b + 0 * NTOK, cnt + 0, lst + 0 * NTOK, 1.0f / (32768.0f * 256.0f));
    cleanup_kernel<256, 512><<<1024, 256, 0, stream>>>(
        x_hand, W_hand, w2_hand, x2b + 0 * NTOK, q_hand, i_hand, loss,
        cnt + 0, lst + 0 * NTOK, 1.0f / (32768.0f * 256.0f));

    vq_mfma<128, 256><<<NTOK / 64, 256, 0, stream>>>(
        x_loc, W_loc, wsp_loc, w2_loc, q_loc, i_loc, loss,
        x2b + 1 * NTOK, cnt + 1, lst + 1 * NTOK, 1.0f / (32768.0f * 128.0f));
    cleanup_kernel<128, 256><<<1024, 256, 0, stream>>>(
        x_loc, W_loc, w2_loc, x2b + 1 * NTOK, q_loc, i_loc, loss,
        cnt + 1, lst + 1 * NTOK, 1.0f / (32768.0f * 128.0f));

    vq_mfma<64, 128><<<NTOK / 64, 256, 0, stream>>>(
        x_ori, W_ori, wsp_ori, w2_ori, q_ori, i_ori, loss,
        x2b + 2 * NTOK, cnt + 2, lst + 2 * NTOK, 1.0f / (32768.0f * 64.0f));
    cleanup_kernel<64, 128><<<1024, 256, 0, stream>>>(
        x_ori, W_ori, w2_ori, x2b + 2 * NTOK, q_ori, i_ori, loss,
        cnt + 2, lst + 2 * NTOK, 1.0f / (32768.0f * 64.0f));

    vq_mfma<128, 256><<<NTOK / 64, 256, 0, stream>>>(
        x_mov, W_mov, wsp_mov, w2_mov, q_mov, i_mov, loss,
        x2b + 3 * NTOK, cnt + 3, lst + 3 * NTOK, 1.0f / (32768.0f * 128.0f));
    cleanup_kernel<128, 256><<<1024, 256, 0, stream>>>(
        x_mov, W_mov, w2_mov, x2b + 3 * NTOK, q_mov, i_mov, loss,
        cnt + 3, lst + 3 * NTOK, 1.0f / (32768.0f * 128.0f));

    vq_mfma<64, 128><<<NTOK / 64, 256, 0, stream>>>(
        x_nmf, W_nmf, wsp_nmf, w2_nmf, q_nmf, i_nmf, loss,
        x2b + 4 * NTOK, cnt + 4, lst + 4 * NTOK, 1.0f / (32768.0f * 64.0f));
    cleanup_kernel<64, 128><<<1024, 256, 0, stream>>>(
        x_nmf, W_nmf, w2_nmf, x2b + 4 * NTOK, q_nmf, i_nmf, loss,
        cnt + 4, lst + 4 * NTOK, 1.0f / (32768.0f * 64.0f));
}

// Round 8
// 316.015 us; speedup vs baseline: 1.1255x; 1.1255x over previous
//
#include <hip/hip_runtime.h>
#include <float.h>

#define NTOK 32768  // 16 * 2048 tokens per modality

typedef __attribute__((ext_vector_type(8))) short bf16x8;
typedef __attribute__((ext_vector_type(4))) float f32x4;

// ---- ws byte layout ----
#define WSB_W2    0          // 1280 floats
#define WSB_X2    8192       // 5*NTOK floats (655360 B)
#define WSB_CNT   663808     // 5 ints
#define WSB_LIST  664064     // 5*NTOK ints (655360 B)
#define WSB_WSP   1572864    // swizzled bf16 hi/lo planes (852 KB)
#define WSB_KEY   2424832    // 5*NTOK u64 argmin keys (1.31 MB)

#define GLOAD16(g, l)                                                        \
  __builtin_amdgcn_global_load_lds(                                          \
      (__attribute__((address_space(1))) const void*)(const void*)(g),       \
      (__attribute__((address_space(3))) void*)(void*)(l), 16, 0, 0)

__device__ __forceinline__ unsigned short f2bf(float f) {
    unsigned u = __float_as_uint(f);
    return (unsigned short)((u + 0x7FFFu + ((u >> 16) & 1u)) >> 16);
}
__device__ __forceinline__ float bf2f(unsigned short h) {
    return __uint_as_float(((unsigned)h) << 16);
}

// ================= numpy pairwise-sum replica (fp32) for ||w||^2 ============
__device__ __forceinline__ float pw_sq_block_g(const float* __restrict__ a, int n) {
    float r[8];
    #pragma unroll
    for (int j = 0; j < 8; ++j) r[j] = __fmul_rn(a[j], a[j]);
    for (int i = 8; i < n; i += 8)
        #pragma unroll
        for (int j = 0; j < 8; ++j)
            r[j] = __fadd_rn(r[j], __fmul_rn(a[i + j], a[i + j]));
    return __fadd_rn(__fadd_rn(__fadd_rn(r[0], r[1]), __fadd_rn(r[2], r[3])),
                     __fadd_rn(__fadd_rn(r[4], r[5]), __fadd_rn(r[6], r[7])));
}

__global__ void w2_kernel(const float* __restrict__ W, float* __restrict__ w2,
                          int K, int D) {
    int k = blockIdx.x * blockDim.x + threadIdx.x;
    if (k >= K) return;
    const float* row = W + (size_t)k * D;
    float s = (D > 128)
        ? __fadd_rn(pw_sq_block_g(row, 128), pw_sq_block_g(row + 128, D - 128))
        : pw_sq_block_g(row, D);
    w2[k] = s;
}

// ---- split W into bf16 hi/lo planes, pre-swizzled per 16-code tile ----
__global__ void wsplit_kernel(const float* __restrict__ W,
                              unsigned char* __restrict__ dst, int K, int D) {
    int i = blockIdx.x * 256 + threadIdx.x;  // element-pair index
    if (i >= K * D / 2) return;
    int k  = i / (D / 2);
    int d2 = i % (D / 2);
    float2 v = *(const float2*)(W + (size_t)k * D + 2 * d2);
    unsigned short h0 = f2bf(v.x), h1 = f2bf(v.y);
    unsigned short l0 = f2bf(__fsub_rn(v.x, bf2f(h0)));
    unsigned short l1 = f2bf(__fsub_rn(v.y, bf2f(h1)));
    int tileb = 16 * D * 2;
    int o  = (k & 15) * (D * 2) + d2 * 4;
    int os = o ^ ((k & 7) << 4);             // XOR swizzle (read side matches)
    size_t tb = (size_t)(k >> 4) * (2 * (size_t)tileb);
    *(unsigned int*)(dst + tb + os)         = (unsigned)h0 | ((unsigned)h1 << 16);
    *(unsigned int*)(dst + tb + tileb + os) = (unsigned)l0 | ((unsigned)l1 << 16);
}

// ---- MFMA bf16-split screen: top-2 argmin + gather + loss ----
template <int D, int K>
__global__ __launch_bounds__(256)
void vq_mfma(const float* __restrict__ X, const float* __restrict__ W,
             const unsigned char* __restrict__ Wsp, const float* __restrict__ w2,
             float* __restrict__ q_out, float* __restrict__ idx_out,
             float* __restrict__ loss_out, float* __restrict__ x2_save,
             int* __restrict__ amb_cnt, int* __restrict__ amb_list,
             float inv_nd)
{
    constexpr int DS    = D / 32;       // MFMA K-steps
    constexpr int NT    = K / 16;       // code tiles
    constexpr int TILEB = 16 * D * 2;   // bytes per plane-tile
    constexpr int STG   = (2 * TILEB) / 4096;  // gload16 iters (256 thr)

    __shared__ __align__(16) unsigned char lds[2 * 2 * TILEB];  // [buf][plane]
    __shared__ int   idx_s[64];
    __shared__ float lred[4];

    const int tid  = threadIdx.x;
    const int lane = tid & 63;
    const int wv   = tid >> 6;
    const int t0   = blockIdx.x * 64;
    const int tw   = t0 + wv * 16 + (lane & 15);   // this lane's token

    // ---- phase 0: numpy-pairwise ||x||^2 (exact replica, lane-split tree) ----
    float x2v;
    {
        const float* xr = X + (size_t)tw * D;
        const int jg = lane >> 4;                  // j-pair group 0..3
        constexpr int B1M = (D > 128) ? 16 : (D / 8);
        float2 v = *(const float2*)(xr + 2 * jg);
        float r0 = __fmul_rn(v.x, v.x), r1 = __fmul_rn(v.y, v.y);
        #pragma unroll
        for (int m = 1; m < B1M; ++m) {
            float2 u = *(const float2*)(xr + 8 * m + 2 * jg);
            r0 = __fadd_rn(r0, __fmul_rn(u.x, u.x));
            r1 = __fadd_rn(r1, __fmul_rn(u.y, u.y));
        }
        float p = __fadd_rn(r0, r1);               // r[2jg]+r[2jg+1]
        p = __fadd_rn(p, __shfl_xor(p, 16, 64));   // (r0+r1)+(r2+r3) | (r4..r7)
        p = __fadd_rn(p, __shfl_xor(p, 32, 64));   // full np combine tree
        x2v = p;
        if (D > 128) {                             // second 128-block (D=256)
            float2 w0 = *(const float2*)(xr + 128 + 2 * jg);
            float s0 = __fmul_rn(w0.x, w0.x), s1 = __fmul_rn(w0.y, w0.y);
            #pragma unroll
            for (int m = 1; m < 16; ++m) {
                float2 u = *(const float2*)(xr + 128 + 8 * m + 2 * jg);
                s0 = __fadd_rn(s0, __fmul_rn(u.x, u.x));
                s1 = __fadd_rn(s1, __fmul_rn(u.y, u.y));
            }
            float q2 = __fadd_rn(s0, s1);
            q2 = __fadd_rn(q2, __shfl_xor(q2, 16, 64));
            q2 = __fadd_rn(q2, __shfl_xor(q2, 32, 64));
            x2v = __fadd_rn(p, q2);
        }
        if ((lane >> 4) == 0) x2_save[tw] = x2v;
    }

    // ---- phase 1: X B-fragments (bf16 hi/lo) into registers ----
    bf16x8 bhi[DS], blo[DS];
    {
        const float* xr = X + (size_t)tw * D + (lane >> 4) * 8;
        #pragma unroll
        for (int ds = 0; ds < DS; ++ds) {
            float4 a = *(const float4*)(xr + ds * 32);
            float4 b = *(const float4*)(xr + ds * 32 + 4);
            float f[8] = {a.x, a.y, a.z, a.w, b.x, b.y, b.z, b.w};
            bf16x8 h, l;
            #pragma unroll
            for (int j = 0; j < 8; ++j) {
                unsigned short hh = f2bf(f[j]);
                h[j] = (short)hh;
                l[j] = (short)f2bf(__fsub_rn(f[j], bf2f(hh)));
            }
            bhi[ds] = h; blo[ds] = l;
        }
    }

    // ---- phase 2: k-loop, double-buffered W tiles, 3-way split MFMA ----
    float b1v = FLT_MAX, b2v = FLT_MAX;
    int   b1i = 0;
    {
        const int row   = lane & 15;               // code within tile
        const int g     = lane >> 4;
        const int abase = row * (D * 2);
        const int sw    = (row & 7) << 4;
        #pragma unroll
        for (int s = 0; s < STG; ++s)
            GLOAD16(Wsp + tid * 16 + s * 4096, lds + tid * 16 + s * 4096);
        __syncthreads();

        for (int kt = 0; kt < NT; ++kt) {
            const int cur = kt & 1;
            if (kt + 1 < NT) {                     // prefetch next tile
                const unsigned char* src = Wsp + (size_t)(kt + 1) * (2 * TILEB);
                unsigned char* dl = lds + (cur ^ 1) * (2 * TILEB);
                #pragma unroll
                for (int s = 0; s < STG; ++s)
                    GLOAD16(src + tid * 16 + s * 4096, dl + tid * 16 + s * 4096);
            }
            const unsigned char* base = lds + cur * (2 * TILEB);
            f32x4 acc0 = {0.f, 0.f, 0.f, 0.f}, acc1 = {0.f, 0.f, 0.f, 0.f};
            #pragma unroll
            for (int ds = 0; ds < DS; ++ds) {
                const int off = (abase + ds * 64 + g * 16) ^ sw;
                bf16x8 ahi = *(const bf16x8*)(base + off);
                bf16x8 alo = *(const bf16x8*)(base + TILEB + off);
                if (ds & 1) {                      // two independent acc chains
                    acc1 = __builtin_amdgcn_mfma_f32_16x16x32_bf16(ahi, bhi[ds], acc1, 0, 0, 0);
                    acc1 = __builtin_amdgcn_mfma_f32_16x16x32_bf16(ahi, blo[ds], acc1, 0, 0, 0);
                    acc1 = __builtin_amdgcn_mfma_f32_16x16x32_bf16(alo, bhi[ds], acc1, 0, 0, 0);
                } else {
                    acc0 = __builtin_amdgcn_mfma_f32_16x16x32_bf16(ahi, bhi[ds], acc0, 0, 0, 0);
                    acc0 = __builtin_amdgcn_mfma_f32_16x16x32_bf16(ahi, blo[ds], acc0, 0, 0, 0);
                    acc0 = __builtin_amdgcn_mfma_f32_16x16x32_bf16(alo, bhi[ds], acc0, 0, 0, 0);
                }
            }
            const int kb = kt * 16 + g * 4;        // codes this lane scored
            #pragma unroll
            for (int r = 0; r < 4; ++r) {          // k-ascending, strict <
                float s = fmaf(-2.f, __fadd_rn(acc0[r], acc1[r]), w2[kb + r]);
                if (s < b1v)      { b2v = b1v; b1v = s; b1i = kb + r; }
                else if (s < b2v) { b2v = s; }
            }
            __syncthreads();
        }
    }

    // ---- phase 3: merge top-2 across the 4 code-groups (tie-break by index) --
    {
        float v1 = b1v, v2 = b2v; int i1 = b1i;
        #pragma unroll
        for (int m = 16; m < 64; m <<= 1) {
            float o1 = __shfl_xor(v1, m, 64);
            float o2 = __shfl_xor(v2, m, 64);
            int   oi = __shfl_xor(i1, m, 64);
            bool better = (o1 < v1) || (o1 == v1 && oi < i1);
            float nb2 = better ? fminf(v1, o2) : fminf(o1, v2);
            if (better) { v1 = o1; i1 = oi; }
            v2 = nb2;
        }
        if ((lane >> 4) == 0) {
            idx_s[tw - t0] = i1;
            idx_out[tw] = (float)i1;
            // per-token margin: np contaminates comparisons by <= 4u*(x2+w2)
            // (u=2^-24); 2.6e-7 = 4u*1.09 headroom; +4e-6 covers screen error
            float margin = fmaf(x2v, 2.6e-7f, 4e-6f);
            if (v2 - v1 <= margin) {               // near-tie: exact rescore
                int p = atomicAdd(amb_cnt, 1);
                amb_list[p] = tw;
            }
        }
    }
    __syncthreads();

    // ---- phase 4: gather q = W[idx] + commitment-loss partial ----
    float lp = 0.f;
    for (int i = tid; i < 64 * (D / 4); i += 256) {
        int d4 = i % (D / 4);
        int t  = i / (D / 4);
        int k  = idx_s[t];
        const float4 w = *(const float4*)(W + (size_t)k * D + d4 * 4);
        const float4 x = *(const float4*)(X + (size_t)(t0 + t) * D + d4 * 4);
        *(float4*)(q_out + (size_t)(t0 + t) * D + d4 * 4) = w;
        float dx;
        dx = w.x - x.x; lp = fmaf(dx, dx, lp);
        dx = w.y - x.y; lp = fmaf(dx, dx, lp);
        dx = w.z - x.z; lp = fmaf(dx, dx, lp);
        dx = w.w - x.w; lp = fmaf(dx, dx, lp);
    }
    #pragma unroll
    for (int off = 32; off > 0; off >>= 1) lp += __shfl_down(lp, off, 64);
    if ((tid & 63) == 0) lred[tid >> 6] = lp;
    __syncthreads();
    if (tid == 0) {
        float tot = (lred[0] + lred[1]) + (lred[2] + lred[3]);
        atomicAdd(loss_out, tot * inv_nd);
    }
}

// ---- exact rescore, stage 1: (token, 16-code chunk) tasks, atomicMin keys ----
// key = (d_bits << 32) | k : d is positive fp32 -> bit-monotone; min key ==
// (min d, then min k) == numpy first-occurrence argmin.
template <int D, int K>
__global__ __launch_bounds__(256)
void cleanup_score(const float* __restrict__ X, const float* __restrict__ W,
                   const float* __restrict__ w2, const float* __restrict__ x2,
                   unsigned long long* __restrict__ keys,
                   const int* __restrict__ cnt, const int* __restrict__ list)
{
    constexpr int NCH = K / 16;   // 16-code chunks per token
    constexpr int EPL = D / 16;   // elems per lane (16 lanes per code)
    const int n     = *cnt;
    const int total = n * NCH;
    const int tid = threadIdx.x;
    const int cg  = tid >> 4;     // code slot 0..15
    const int sub = tid & 15;

    for (int task = blockIdx.x; task < total; task += gridDim.x) {
        const int e  = task / NCH;
        const int ch = task % NCH;
        const int t  = list[e];
        const int k  = ch * 16 + cg;
        const float* xp = X + (size_t)t * D + sub * EPL;
        const float* wp = W + (size_t)k * D + sub * EPL;
        double a = 0.0;
        #pragma unroll
        for (int j = 0; j < EPL / 4; ++j) {
            const float4 xv = *(const float4*)(xp + j * 4);
            const float4 wv = *(const float4*)(wp + j * 4);
            a = fma((double)xv.x, (double)wv.x, a);
            a = fma((double)xv.y, (double)wv.y, a);
            a = fma((double)xv.z, (double)wv.z, a);
            a = fma((double)xv.w, (double)wv.w, a);
        }
        a += __shfl_down(a, 8, 16);
        a += __shfl_down(a, 4, 16);
        a += __shfl_down(a, 2, 16);
        a += __shfl_down(a, 1, 16);
        if (sub == 0) {
            const float m = (float)a;                      // fl32(f64 dot)
            const float d = __fsub_rn(__fadd_rn(x2[t], w2[k]),
                                      __fmul_rn(2.0f, m)); // np-replica fp32
            unsigned long long key =
                ((unsigned long long)__float_as_uint(d) << 32) | (unsigned)k;
            atomicMin(&keys[e], key);
        }
    }
}

// ---- exact rescore, stage 2: patch idx / q row / loss for changed tokens ----
template <int D>
__global__ __launch_bounds__(256)
void cleanup_apply(const float* __restrict__ X, const float* __restrict__ W,
                   const unsigned long long* __restrict__ keys,
                   const int* __restrict__ cnt, const int* __restrict__ list,
                   float* __restrict__ q_out, float* __restrict__ idx_out,
                   float* __restrict__ loss_out, float inv_nd)
{
    const int n   = *cnt;
    const int tid = threadIdx.x;
    for (int e = blockIdx.x; e < n; e += gridDim.x) {
        const int t    = list[e];
        const int bk   = (int)(unsigned)(keys[e] & 0xFFFFFFFFull);
        const int oldk = (int)idx_out[t];   // all threads read BEFORE any write
        __syncthreads();
        if (bk == oldk) continue;           // uniform across block
        if (tid == 0) idx_out[t] = (float)bk;
        const float* xr = X + (size_t)t * D;
        const float* wn = W + (size_t)bk * D;
        const float* wo = W + (size_t)oldk * D;
        float dl = 0.f;
        for (int d = tid; d < D; d += 256) {
            float xv = xr[d], a = wn[d], b = wo[d];
            q_out[(size_t)t * D + d] = a;
            float da = a - xv, db = b - xv;
            dl += da * da - db * db;
        }
        #pragma unroll
        for (int off = 32; off; off >>= 1) dl += __shfl_down(dl, off, 64);
        if ((tid & 63) == 0 && dl != 0.f) atomicAdd(loss_out, dl * inv_nd);
    }
}

extern "C" void kernel_launch(void* const* d_in, const int* in_sizes, int n_in,
                              void* d_out, int out_size, void* d_ws, size_t ws_size,
                              hipStream_t stream)
{
    const float* x_hand = (const float*)d_in[0];
    const float* W_hand = (const float*)d_in[1];
    const float* x_loc  = (const float*)d_in[2];
    const float* W_loc  = (const float*)d_in[3];
    const float* x_ori  = (const float*)d_in[4];
    const float* W_ori  = (const float*)d_in[5];
    const float* x_mov  = (const float*)d_in[6];
    const float* W_mov  = (const float*)d_in[7];
    const float* x_nmf  = (const float*)d_in[8];
    const float* W_nmf  = (const float*)d_in[9];

    float* out = (float*)d_out;
    float* q_hand = out;
    float* q_loc  = out + 8388608;
    float* q_ori  = out + 12582912;
    float* q_mov  = out + 14680064;
    float* q_nmf  = out + 18874368;
    float* i_hand = out + 20971520;
    float* i_loc  = out + 21004288;
    float* i_ori  = out + 21037056;
    float* i_mov  = out + 21069824;
    float* i_nmf  = out + 21102592;
    float* loss   = out + 21135360;

    unsigned char* wsb = (unsigned char*)d_ws;
    float* w2b = (float*)(wsb + WSB_W2);
    float* w2_hand = w2b, *w2_loc = w2b + 512, *w2_ori = w2b + 768,
         * w2_mov = w2b + 896, *w2_nmf = w2b + 1152;
    float* x2b = (float*)(wsb + WSB_X2);
    int*   cnt = (int*)(wsb + WSB_CNT);
    int*   lst = (int*)(wsb + WSB_LIST);
    unsigned char* wsp_hand = wsb + WSB_WSP;            // 512*256*2*2 = 524288
    unsigned char* wsp_loc  = wsp_hand + 524288;        // 131072
    unsigned char* wsp_ori  = wsp_loc + 131072;         // 32768
    unsigned char* wsp_mov  = wsp_ori + 32768;          // 131072
    unsigned char* wsp_nmf  = wsp_mov + 131072;         // 32768
    unsigned long long* keys = (unsigned long long*)(wsb + WSB_KEY);

    hipMemsetAsync(loss, 0, sizeof(float), stream);
    hipMemsetAsync(cnt, 0, 5 * sizeof(int), stream);
    hipMemsetAsync(keys, 0xFF, 5 * (size_t)NTOK * 8, stream);

    w2_kernel<<<2, 256, 0, stream>>>(W_hand, w2_hand, 512, 256);
    w2_kernel<<<1, 256, 0, stream>>>(W_loc,  w2_loc,  256, 128);
    w2_kernel<<<1, 256, 0, stream>>>(W_ori,  w2_ori,  128, 64);
    w2_kernel<<<1, 256, 0, stream>>>(W_mov,  w2_mov,  256, 128);
    w2_kernel<<<1, 256, 0, stream>>>(W_nmf,  w2_nmf,  128, 64);

    wsplit_kernel<<<256, 256, 0, stream>>>(W_hand, wsp_hand, 512, 256);
    wsplit_kernel<<<64,  256, 0, stream>>>(W_loc,  wsp_loc,  256, 128);
    wsplit_kernel<<<16,  256, 0, stream>>>(W_ori,  wsp_ori,  128, 64);
    wsplit_kernel<<<64,  256, 0, stream>>>(W_mov,  wsp_mov,  256, 128);
    wsplit_kernel<<<16,  256, 0, stream>>>(W_nmf,  wsp_nmf,  128, 64);

    vq_mfma<256, 512><<<NTOK / 64, 256, 0, stream>>>(
        x_hand, W_hand, wsp_hand, w2_hand, q_hand, i_hand, loss,
        x2b + 0 * NTOK, cnt + 0, lst + 0 * NTOK, 1.0f / (32768.0f * 256.0f));
    cleanup_score<256, 512><<<2048, 256, 0, stream>>>(
        x_hand, W_hand, w2_hand, x2b + 0 * NTOK, keys + 0 * NTOK,
        cnt + 0, lst + 0 * NTOK);
    cleanup_apply<256><<<1024, 256, 0, stream>>>(
        x_hand, W_hand, keys + 0 * NTOK, cnt + 0, lst + 0 * NTOK,
        q_hand, i_hand, loss, 1.0f / (32768.0f * 256.0f));

    vq_mfma<128, 256><<<NTOK / 64, 256, 0, stream>>>(
        x_loc, W_loc, wsp_loc, w2_loc, q_loc, i_loc, loss,
        x2b + 1 * NTOK, cnt + 1, lst + 1 * NTOK, 1.0f / (32768.0f * 128.0f));
    cleanup_score<128, 256><<<2048, 256, 0, stream>>>(
        x_loc, W_loc, w2_loc, x2b + 1 * NTOK, keys + 1 * NTOK,
        cnt + 1, lst + 1 * NTOK);
    cleanup_apply<128><<<1024, 256, 0, stream>>>(
        x_loc, W_loc, keys + 1 * NTOK, cnt + 1, lst + 1 * NTOK,
        q_loc, i_loc, loss, 1.0f / (32768.0f * 128.0f));

    vq_mfma<64, 128><<<NTOK / 64, 256, 0, stream>>>(
        x_ori, W_ori, wsp_ori, w2_ori, q_ori, i_ori, loss,
        x2b + 2 * NTOK, cnt + 2, lst + 2 * NTOK, 1.0f / (32768.0f * 64.0f));
    cleanup_score<64, 128><<<2048, 256, 0, stream>>>(
        x_ori, W_ori, w2_ori, x2b + 2 * NTOK, keys + 2 * NTOK,
        cnt + 2, lst + 2 * NTOK);
    cleanup_apply<64><<<1024, 256, 0, stream>>>(
        x_ori, W_ori, keys + 2 * NTOK, cnt + 2, lst + 2 * NTOK,
        q_ori, i_ori, loss, 1.0f / (32768.0f * 64.0f));

    vq_mfma<128, 256><<<NTOK / 64, 256, 0, stream>>>(
        x_mov, W_mov, wsp_mov, w2_mov, q_mov, i_mov, loss,
        x2b + 3 * NTOK, cnt + 3, lst + 3 * NTOK, 1.0f / (32768.0f * 128.0f));
    cleanup_score<128, 256><<<2048, 256, 0, stream>>>(
        x_mov, W_mov, w2_mov, x2b + 3 * NTOK, keys + 3 * NTOK,
        cnt + 3, lst + 3 * NTOK);
    cleanup_apply<128><<<1024, 256, 0, stream>>>(
        x_mov, W_mov, keys + 3 * NTOK, cnt + 3, lst + 3 * NTOK,
        q_mov, i_mov, loss, 1.0f / (32768.0f * 128.0f));

    vq_mfma<64, 128><<<NTOK / 64, 256, 0, stream>>>(
        x_nmf, W_nmf, wsp_nmf, w2_nmf, q_nmf, i_nmf, loss,
        x2b + 4 * NTOK, cnt + 4, lst + 4 * NTOK, 1.0f / (32768.0f * 64.0f));
    cleanup_score<64, 128><<<2048, 256, 0, stream>>>(
        x_nmf, W_nmf, w2_nmf, x2b + 4 * NTOK, keys + 4 * NTOK,
        cnt + 4, lst + 4 * NTOK);
    cleanup_apply<64><<<1024, 256, 0, stream>>>(
        x_nmf, W_nmf, keys + 4 * NTOK, cnt + 4, lst + 4 * NTOK,
        q_nmf, i_nmf, loss, 1.0f / (32768.0f * 64.0f));
}

// Round 9
// 265.157 us; speedup vs baseline: 1.3414x; 1.1918x over previous
//
#include <hip/hip_runtime.h>
#include <float.h>

#define NTOK 32768  // 16 * 2048 tokens per modality

typedef __attribute__((ext_vector_type(8))) short bf16x8;
typedef __attribute__((ext_vector_type(4))) float f32x4;

// ---- ws byte layout ----
#define WSB_W2    0          // 1280 floats
#define WSB_X2    8192       // 5*NTOK floats
#define WSB_CNT   663808     // 5 ints
#define WSB_LIST  664064     // 5*NTOK ints
#define WSB_WSP   1572864    // swizzled bf16 hi/lo planes (852 KB)
#define WSB_KEY   2424832    // 5*NTOK u64 argmin keys

#define GLOAD16(g, l)                                                        \
  __builtin_amdgcn_global_load_lds(                                          \
      (__attribute__((address_space(1))) const void*)(const void*)(g),       \
      (__attribute__((address_space(3))) void*)(void*)(l), 16, 0, 0)

struct AllPtrs {
    const float* X[5];
    const float* W[5];
    unsigned char* Wsp[5];
    float* w2[5];
    float* q[5];
    float* idx[5];
    float* x2[5];
    int* cnt;
    int* lst;                  // + m*NTOK
    unsigned long long* keys;  // + m*NTOK
    float* loss;
};

__device__ __forceinline__ unsigned short f2bf(float f) {
    unsigned u = __float_as_uint(f);
    return (unsigned short)((u + 0x7FFFu + ((u >> 16) & 1u)) >> 16);
}
__device__ __forceinline__ float bf2f(unsigned short h) {
    return __uint_as_float(((unsigned)h) << 16);
}

// ============ numpy pairwise-sum replica (fp32, PW_BLOCKSIZE=128) ===========
__device__ __forceinline__ float pw_sq_block_g(const float* __restrict__ a, int n) {
    float r[8];
    #pragma unroll
    for (int j = 0; j < 8; ++j) r[j] = __fmul_rn(a[j], a[j]);
    for (int i = 8; i < n; i += 8)
        #pragma unroll
        for (int j = 0; j < 8; ++j)
            r[j] = __fadd_rn(r[j], __fmul_rn(a[i + j], a[i + j]));
    return __fadd_rn(__fadd_rn(__fadd_rn(r[0], r[1]), __fadd_rn(r[2], r[3])),
                     __fadd_rn(__fadd_rn(r[4], r[5]), __fadd_rn(r[6], r[7])));
}

template <int D>
__device__ __forceinline__ void w2_body(const float* __restrict__ W,
                                        float* __restrict__ w2, int k, int K) {
    if (k >= K) return;
    const float* row = W + (size_t)k * D;
    float s = (D > 128)
        ? __fadd_rn(pw_sq_block_g(row, 128), pw_sq_block_g(row + 128, D - 128))
        : pw_sq_block_g(row, D);
    w2[k] = s;
}

template <int D, int K>
__device__ __forceinline__ void wsplit_body(const float* __restrict__ W,
                                            unsigned char* __restrict__ dst, int i) {
    if (i >= K * D / 2) return;
    int k  = i / (D / 2);
    int d2 = i % (D / 2);
    float2 v = *(const float2*)(W + (size_t)k * D + 2 * d2);
    unsigned short h0 = f2bf(v.x), h1 = f2bf(v.y);
    unsigned short l0 = f2bf(__fsub_rn(v.x, bf2f(h0)));
    unsigned short l1 = f2bf(__fsub_rn(v.y, bf2f(h1)));
    int tileb = 16 * D * 2;
    int o  = (k & 15) * (D * 2) + d2 * 4;
    int os = o ^ ((k & 7) << 4);
    size_t tb = (size_t)(k >> 4) * (2 * (size_t)tileb);
    *(unsigned int*)(dst + tb + os)         = (unsigned)h0 | ((unsigned)h1 << 16);
    *(unsigned int*)(dst + tb + tileb + os) = (unsigned)l0 | ((unsigned)l1 << 16);
}

// ---- prep: zero loss/cnt, w2 (np-replica), W bf16-split planes -------------
__global__ __launch_bounds__(256) void prep_mega(AllPtrs P) {
    const int bid = blockIdx.x, tid = threadIdx.x;
    if (bid == 0 && tid == 0) *P.loss = 0.f;
    if (bid == 0 && tid < 5) P.cnt[tid] = 0;
    if (bid < 6) {
        if (bid < 2)      w2_body<256>(P.W[0], P.w2[0], bid * 256 + tid, 512);
        else if (bid == 2) w2_body<128>(P.W[1], P.w2[1], tid, 256);
        else if (bid == 3) w2_body<64> (P.W[2], P.w2[2], tid, 128);
        else if (bid == 4) w2_body<128>(P.W[3], P.w2[3], tid, 256);
        else               w2_body<64> (P.W[4], P.w2[4], tid, 128);
    } else {
        int b = bid - 6;
        if (b < 256)      wsplit_body<256, 512>(P.W[0], P.Wsp[0], b * 256 + tid);
        else if (b < 320) wsplit_body<128, 256>(P.W[1], P.Wsp[1], (b - 256) * 256 + tid);
        else if (b < 336) wsplit_body<64, 128> (P.W[2], P.Wsp[2], (b - 320) * 256 + tid);
        else if (b < 400) wsplit_body<128, 256>(P.W[3], P.Wsp[3], (b - 336) * 256 + tid);
        else              wsplit_body<64, 128> (P.W[4], P.Wsp[4], (b - 400) * 256 + tid);
    }
}

// ---- numpy-pairwise ||x||^2 replica, wave-cooperative (all lanes get it) ---
template <int D>
__device__ __forceinline__ float x2_replica(const float* __restrict__ xr, int lane) {
    const int jg = lane >> 4;
    constexpr int B1M = (D > 128) ? 16 : (D / 8);
    float2 v = *(const float2*)(xr + 2 * jg);
    float r0 = __fmul_rn(v.x, v.x), r1 = __fmul_rn(v.y, v.y);
    #pragma unroll
    for (int m = 1; m < B1M; ++m) {
        float2 u = *(const float2*)(xr + 8 * m + 2 * jg);
        r0 = __fadd_rn(r0, __fmul_rn(u.x, u.x));
        r1 = __fadd_rn(r1, __fmul_rn(u.y, u.y));
    }
    float p = __fadd_rn(r0, r1);
    p = __fadd_rn(p, __shfl_xor(p, 16, 64));
    p = __fadd_rn(p, __shfl_xor(p, 32, 64));
    if (D > 128) {
        float2 w0 = *(const float2*)(xr + 128 + 2 * jg);
        float s0 = __fmul_rn(w0.x, w0.x), s1 = __fmul_rn(w0.y, w0.y);
        #pragma unroll
        for (int m = 1; m < 16; ++m) {
            float2 u = *(const float2*)(xr + 128 + 8 * m + 2 * jg);
            s0 = __fadd_rn(s0, __fmul_rn(u.x, u.x));
            s1 = __fadd_rn(s1, __fmul_rn(u.y, u.y));
        }
        float q2 = __fadd_rn(s0, s1);
        q2 = __fadd_rn(q2, __shfl_xor(q2, 16, 64));
        q2 = __fadd_rn(q2, __shfl_xor(q2, 32, 64));
        p = __fadd_rn(p, q2);
    }
    return p;
}

__device__ __forceinline__ float merge_flag_set(
    float b1v, float b2v, int b1i, float x2v, int tw, int t0, int lane,
    int* idx_s, float* idx_m, int* cnt_m, int* lst_m,
    unsigned long long* keys_m)
{
    float v1 = b1v, v2 = b2v; int i1 = b1i;
    #pragma unroll
    for (int m = 16; m < 64; m <<= 1) {
        float o1 = __shfl_xor(v1, m, 64);
        float o2 = __shfl_xor(v2, m, 64);
        int   oi = __shfl_xor(i1, m, 64);
        bool better = (o1 < v1) || (o1 == v1 && oi < i1);
        float nb2 = better ? fminf(v1, o2) : fminf(o1, v2);
        if (better) { v1 = o1; i1 = oi; }
        v2 = nb2;
    }
    float lterm = 0.f;
    if ((lane >> 4) == 0) {
        idx_s[tw - t0] = i1;
        idx_m[tw] = (float)i1;
        lterm = __fadd_rn(x2v, v1);          // d_min (screen-accurate)
        float margin = fmaf(x2v, 2.6e-7f, 4e-6f);
        if (v2 - v1 <= margin) {             // near-tie: exact rescore later
            int p = atomicAdd(cnt_m, 1);
            lst_m[p] = tw;
            keys_m[p] = ~0ULL;
        }
    }
    return lterm;
}

// ---- MFMA bf16-split screen body: 128 tok/block, 2 token-sets/wave ---------
template <int D, int K, int M>
__device__ void vq_body(const AllPtrs& P, int bid, unsigned char* lds, int* idx_s)
{
    constexpr int DS    = D / 32;
    constexpr int NT    = K / 16;
    constexpr int TILEB = 16 * D * 2;
    constexpr int STG   = (2 * TILEB) / 4096;
    const float inv_nd = 1.0f / (32768.0f * (float)D);

    const float* X   = P.X[M];
    const float* W   = P.W[M];
    const unsigned char* Wsp = P.Wsp[M];
    const float* w2  = P.w2[M];
    float* q_out     = P.q[M];
    float* idx_out   = P.idx[M];
    float* x2_save   = P.x2[M];
    int*   cnt_m     = P.cnt + M;
    int*   lst_m     = P.lst + M * NTOK;
    unsigned long long* keys_m = P.keys + M * NTOK;

    const int tid  = threadIdx.x;
    const int lane = tid & 63;
    const int wv   = tid >> 6;
    const int t0   = bid * 128;
    const int tb   = t0 + wv * 32;
    const int tw0  = tb + (lane & 15);
    const int tw1  = tw0 + 16;

    // phase 0: np-replica ||x||^2 for both token sets
    const float x2v0 = x2_replica<D>(X + (size_t)tw0 * D, lane);
    const float x2v1 = x2_replica<D>(X + (size_t)tw1 * D, lane);
    if ((lane >> 4) == 0) { x2_save[tw0] = x2v0; x2_save[tw1] = x2v1; }

    // phase 1: X B-fragments (bf16 hi/lo), 2 sets
    bf16x8 bhi0[DS], blo0[DS], bhi1[DS], blo1[DS];
    {
        const float* xr0 = X + (size_t)tw0 * D + (lane >> 4) * 8;
        const float* xr1 = X + (size_t)tw1 * D + (lane >> 4) * 8;
        #pragma unroll
        for (int ds = 0; ds < DS; ++ds) {
            #pragma unroll
            for (int s = 0; s < 2; ++s) {
                const float* xr = s ? xr1 : xr0;
                float4 a = *(const float4*)(xr + ds * 32);
                float4 b = *(const float4*)(xr + ds * 32 + 4);
                float f[8] = {a.x, a.y, a.z, a.w, b.x, b.y, b.z, b.w};
                bf16x8 h, l;
                #pragma unroll
                for (int j = 0; j < 8; ++j) {
                    unsigned short hh = f2bf(f[j]);
                    h[j] = (short)hh;
                    l[j] = (short)f2bf(__fsub_rn(f[j], bf2f(hh)));
                }
                if (s) { bhi1[ds] = h; blo1[ds] = l; }
                else   { bhi0[ds] = h; blo0[ds] = l; }
            }
        }
    }

    // phase 2: k-loop, double-buffered W tiles, 3-way split MFMA, 2 token sets
    float b1v0 = FLT_MAX, b2v0 = FLT_MAX, b1v1 = FLT_MAX, b2v1 = FLT_MAX;
    int   b1i0 = 0, b1i1 = 0;
    {
        const int row   = lane & 15;
        const int g     = lane >> 4;
        const int abase = row * (D * 2);
        const int sw    = (row & 7) << 4;
        #pragma unroll
        for (int s = 0; s < STG; ++s)
            GLOAD16(Wsp + tid * 16 + s * 4096, lds + tid * 16 + s * 4096);
        __syncthreads();

        for (int kt = 0; kt < NT; ++kt) {
            const int cur = kt & 1;
            if (kt + 1 < NT) {
                const unsigned char* src = Wsp + (size_t)(kt + 1) * (2 * TILEB);
                unsigned char* dl = lds + (cur ^ 1) * (2 * TILEB);
                #pragma unroll
                for (int s = 0; s < STG; ++s)
                    GLOAD16(src + tid * 16 + s * 4096, dl + tid * 16 + s * 4096);
            }
            const unsigned char* base = lds + cur * (2 * TILEB);
            f32x4 a00 = {0,0,0,0}, a01 = {0,0,0,0};   // set0 parity chains
            f32x4 a10 = {0,0,0,0}, a11 = {0,0,0,0};   // set1 parity chains
            #pragma unroll
            for (int ds = 0; ds < DS; ++ds) {
                const int off = (abase + ds * 64 + g * 16) ^ sw;
                bf16x8 ahi = *(const bf16x8*)(base + off);
                bf16x8 alo = *(const bf16x8*)(base + TILEB + off);
                if (ds & 1) {
                    a01 = __builtin_amdgcn_mfma_f32_16x16x32_bf16(ahi, bhi0[ds], a01, 0, 0, 0);
                    a11 = __builtin_amdgcn_mfma_f32_16x16x32_bf16(ahi, bhi1[ds], a11, 0, 0, 0);
                    a01 = __builtin_amdgcn_mfma_f32_16x16x32_bf16(ahi, blo0[ds], a01, 0, 0, 0);
                    a11 = __builtin_amdgcn_mfma_f32_16x16x32_bf16(ahi, blo1[ds], a11, 0, 0, 0);
                    a01 = __builtin_amdgcn_mfma_f32_16x16x32_bf16(alo, bhi0[ds], a01, 0, 0, 0);
                    a11 = __builtin_amdgcn_mfma_f32_16x16x32_bf16(alo, bhi1[ds], a11, 0, 0, 0);
                } else {
                    a00 = __builtin_amdgcn_mfma_f32_16x16x32_bf16(ahi, bhi0[ds], a00, 0, 0, 0);
                    a10 = __builtin_amdgcn_mfma_f32_16x16x32_bf16(ahi, bhi1[ds], a10, 0, 0, 0);
                    a00 = __builtin_amdgcn_mfma_f32_16x16x32_bf16(ahi, blo0[ds], a00, 0, 0, 0);
                    a10 = __builtin_amdgcn_mfma_f32_16x16x32_bf16(ahi, blo1[ds], a10, 0, 0, 0);
                    a00 = __builtin_amdgcn_mfma_f32_16x16x32_bf16(alo, bhi0[ds], a00, 0, 0, 0);
                    a10 = __builtin_amdgcn_mfma_f32_16x16x32_bf16(alo, bhi1[ds], a10, 0, 0, 0);
                }
            }
            const int kb = kt * 16 + g * 4;
            #pragma unroll
            for (int r = 0; r < 4; ++r) {              // k-ascending, strict <
                float s0 = fmaf(-2.f, __fadd_rn(a00[r], a01[r]), w2[kb + r]);
                if (s0 < b1v0)      { b2v0 = b1v0; b1v0 = s0; b1i0 = kb + r; }
                else if (s0 < b2v0) { b2v0 = s0; }
                float s1 = fmaf(-2.f, __fadd_rn(a10[r], a11[r]), w2[kb + r]);
                if (s1 < b1v1)      { b2v1 = b1v1; b1v1 = s1; b1i1 = kb + r; }
                else if (s1 < b2v1) { b2v1 = s1; }
            }
            __syncthreads();
        }
    }

    // phase 3: merge top-2 across code groups; flag; loss from screen d_min
    float ls = merge_flag_set(b1v0, b2v0, b1i0, x2v0, tw0, t0, lane,
                              idx_s, idx_out, cnt_m, lst_m, keys_m)
             + merge_flag_set(b1v1, b2v1, b1i1, x2v1, tw1, t0, lane,
                              idx_s, idx_out, cnt_m, lst_m, keys_m);
    #pragma unroll
    for (int off = 32; off > 0; off >>= 1) ls += __shfl_down(ls, off, 64);
    if (lane == 0) atomicAdd(P.loss, ls * inv_nd);
    __syncthreads();

    // phase 4: gather q = W[idx] (pure gather+write; no X re-read)
    for (int i = tid; i < 128 * (D / 4); i += 256) {
        int d4 = i % (D / 4);
        int t  = i / (D / 4);
        int k  = idx_s[t];
        const float4 w = *(const float4*)(W + (size_t)k * D + d4 * 4);
        *(float4*)(q_out + (size_t)(t0 + t) * D + d4 * 4) = w;
    }
}

__global__ __launch_bounds__(256) void vq_mega(AllPtrs P) {
    __shared__ __align__(16) unsigned char lds[32768];
    __shared__ int idx_s[128];
    const int bid = blockIdx.x;
    if (bid < 256)       vq_body<256, 512, 0>(P, bid,        lds, idx_s);
    else if (bid < 512)  vq_body<128, 256, 1>(P, bid - 256,  lds, idx_s);
    else if (bid < 768)  vq_body<64,  128, 2>(P, bid - 512,  lds, idx_s);
    else if (bid < 1024) vq_body<128, 256, 3>(P, bid - 768,  lds, idx_s);
    else                 vq_body<64,  128, 4>(P, bid - 1024, lds, idx_s);
}

// ---- cleanup stage 1: (token, 16-code chunk) tasks, atomicMin keys ---------
template <int D, int K, int M>
__device__ void score_body(const AllPtrs& P, int sbid, int sblk)
{
    constexpr int NCH = K / 16;
    constexpr int EPL = D / 16;
    const float* X  = P.X[M];
    const float* W  = P.W[M];
    const float* w2 = P.w2[M];
    const float* x2 = P.x2[M];
    const int* list = P.lst + M * NTOK;
    unsigned long long* keys = P.keys + M * NTOK;
    const int n     = P.cnt[M];
    const int total = n * NCH;
    const int tid = threadIdx.x;
    const int cg  = tid >> 4;
    const int sub = tid & 15;

    for (int task = sbid; task < total; task += sblk) {
        const int e  = task / NCH;
        const int ch = task % NCH;
        const int t  = list[e];
        const int k  = ch * 16 + cg;
        const float* xp = X + (size_t)t * D + sub * EPL;
        const float* wp = W + (size_t)k * D + sub * EPL;
        double a = 0.0;
        #pragma unroll
        for (int j = 0; j < EPL / 4; ++j) {
            const float4 xv = *(const float4*)(xp + j * 4);
            const float4 wv = *(const float4*)(wp + j * 4);
            a = fma((double)xv.x, (double)wv.x, a);
            a = fma((double)xv.y, (double)wv.y, a);
            a = fma((double)xv.z, (double)wv.z, a);
            a = fma((double)xv.w, (double)wv.w, a);
        }
        a += __shfl_down(a, 8, 16);
        a += __shfl_down(a, 4, 16);
        a += __shfl_down(a, 2, 16);
        a += __shfl_down(a, 1, 16);
        if (sub == 0) {
            const float m = (float)a;
            const float d = __fsub_rn(__fadd_rn(x2[t], w2[k]),
                                      __fmul_rn(2.0f, m));
            unsigned long long key =
                ((unsigned long long)__float_as_uint(d) << 32) | (unsigned)k;
            atomicMin(&keys[e], key);
        }
    }
}

__global__ __launch_bounds__(256) void score_mega(AllPtrs P) {
    const int bid = blockIdx.x;
    if (bid < 1024)      score_body<256, 512, 0>(P, bid,        1024);
    else if (bid < 1536) score_body<128, 256, 1>(P, bid - 1024, 512);
    else if (bid < 1792) score_body<64,  128, 2>(P, bid - 1536, 256);
    else if (bid < 2304) score_body<128, 256, 3>(P, bid - 1792, 512);
    else                 score_body<64,  128, 4>(P, bid - 2304, 256);
}

// ---- cleanup stage 2: patch idx / q row / loss for changed tokens ----------
template <int D, int M>
__device__ void apply_body(const AllPtrs& P, int sbid, int sblk)
{
    const float* X = P.X[M];
    const float* W = P.W[M];
    float* q_out   = P.q[M];
    float* idx_out = P.idx[M];
    const int* list = P.lst + M * NTOK;
    const unsigned long long* keys = P.keys + M * NTOK;
    const float inv_nd = 1.0f / (32768.0f * (float)D);
    const int n   = P.cnt[M];
    const int tid = threadIdx.x;

    for (int e = sbid; e < n; e += sblk) {
        const int t    = list[e];
        const int bk   = (int)(unsigned)(keys[e] & 0xFFFFFFFFull);
        const int oldk = (int)idx_out[t];   // all threads read BEFORE write
        __syncthreads();
        if (bk == oldk) continue;           // uniform across block
        if (tid == 0) idx_out[t] = (float)bk;
        const float* xr = X + (size_t)t * D;
        const float* wn = W + (size_t)bk * D;
        const float* wo = W + (size_t)oldk * D;
        float dl = 0.f;
        for (int d = tid; d < D; d += 256) {
            float xv = xr[d], a = wn[d], b = wo[d];
            q_out[(size_t)t * D + d] = a;
            float da = a - xv, db = b - xv;
            dl += da * da - db * db;
        }
        #pragma unroll
        for (int off = 32; off; off >>= 1) dl += __shfl_down(dl, off, 64);
        if ((tid & 63) == 0 && dl != 0.f) atomicAdd(P.loss, dl * inv_nd);
    }
}

__global__ __launch_bounds__(256) void apply_mega(AllPtrs P) {
    const int bid = blockIdx.x;
    if (bid < 256)       apply_body<256, 0>(P, bid,       256);
    else if (bid < 512)  apply_body<128, 1>(P, bid - 256, 256);
    else if (bid < 768)  apply_body<64,  2>(P, bid - 512, 256);
    else if (bid < 1024) apply_body<128, 3>(P, bid - 768, 256);
    else                 apply_body<64,  4>(P, bid - 1024, 256);
}

extern "C" void kernel_launch(void* const* d_in, const int* in_sizes, int n_in,
                              void* d_out, int out_size, void* d_ws, size_t ws_size,
                              hipStream_t stream)
{
    float* out = (float*)d_out;
    unsigned char* wsb = (unsigned char*)d_ws;
    float* w2b = (float*)(wsb + WSB_W2);

    AllPtrs P;
    P.X[0] = (const float*)d_in[0]; P.W[0] = (const float*)d_in[1];
    P.X[1] = (const float*)d_in[2]; P.W[1] = (const float*)d_in[3];
    P.X[2] = (const float*)d_in[4]; P.W[2] = (const float*)d_in[5];
    P.X[3] = (const float*)d_in[6]; P.W[3] = (const float*)d_in[7];
    P.X[4] = (const float*)d_in[8]; P.W[4] = (const float*)d_in[9];

    P.q[0] = out;            P.q[1] = out + 8388608;  P.q[2] = out + 12582912;
    P.q[3] = out + 14680064; P.q[4] = out + 18874368;
    P.idx[0] = out + 20971520; P.idx[1] = out + 21004288;
    P.idx[2] = out + 21037056; P.idx[3] = out + 21069824;
    P.idx[4] = out + 21102592;
    P.loss = out + 21135360;

    P.w2[0] = w2b;       P.w2[1] = w2b + 512; P.w2[2] = w2b + 768;
    P.w2[3] = w2b + 896; P.w2[4] = w2b + 1152;
    float* x2b = (float*)(wsb + WSB_X2);
    for (int m = 0; m < 5; ++m) P.x2[m] = x2b + m * NTOK;
    P.cnt  = (int*)(wsb + WSB_CNT);
    P.lst  = (int*)(wsb + WSB_LIST);
    P.keys = (unsigned long long*)(wsb + WSB_KEY);
    P.Wsp[0] = wsb + WSB_WSP;            // 512*256*2*2 = 524288
    P.Wsp[1] = P.Wsp[0] + 524288;        // 131072
    P.Wsp[2] = P.Wsp[1] + 131072;        // 32768
    P.Wsp[3] = P.Wsp[2] + 32768;         // 131072
    P.Wsp[4] = P.Wsp[3] + 131072;        // 32768

    prep_mega <<<422,  256, 0, stream>>>(P);
    vq_mega   <<<1280, 256, 0, stream>>>(P);
    score_mega<<<2560, 256, 0, stream>>>(P);
    apply_mega<<<1280, 256, 0, stream>>>(P);
}